// Round 13
// baseline (205.631 us; speedup 1.0000x reference)
//
#include <hip/hip_runtime.h>
#include <hip/hip_bf16.h>

// out[s,o] = sum_k x[s,k]*W[o,k]   (bf16 MFMA)
//   128x128 tile, BK=64, 8 waves (64x32 wave tile), split-K=4.
//   x: bf16 via global_load_lds ring-3. W: fp32 inline-asm loads 1 phase ahead
//   -> cvt_pk -> ds_write (2-slot bf16 LDS). Counted per-wave VMCNT(6).
//   Split-K reduction FUSED via last-block-reduces (device-scope fences +
//   per-tile atomic counter, fixed-order sum for determinism).
// + zc_w*8*sum_r A[o,r]*t[r,s] + zc_b*xsum[s] + bias[o] exact fp32 epilogue.

typedef __attribute__((ext_vector_type(8))) short bf16x8;
typedef __attribute__((ext_vector_type(4))) short bf16x4;
typedef __attribute__((ext_vector_type(4))) unsigned short u16x4;
typedef __attribute__((ext_vector_type(4))) float f32x4;

#define MDIM 512
#define NDIM 4096
#define KDIM 4096
#define BM 128
#define BN 128
#define BK 64
#define NT (KDIM / BK)   // 64

#define VMCNT(n) asm volatile("s_waitcnt vmcnt(" #n ")" ::: "memory")
#define LGKM0()  asm volatile("s_waitcnt lgkmcnt(0)" ::: "memory")
#define SCHED0() __builtin_amdgcn_sched_barrier(0)

static __device__ inline unsigned short f2bf(float f) {
  return __bfloat16_as_ushort(__float2bfloat16(f));  // v_cvt_pk_bf16_f32
}

static __device__ inline bf16x8 pack8(f32x4 a, f32x4 b) {
  bf16x8 v;
  v[0] = (short)f2bf(a[0]); v[1] = (short)f2bf(a[1]);
  v[2] = (short)f2bf(a[2]); v[3] = (short)f2bf(a[3]);
  v[4] = (short)f2bf(b[0]); v[5] = (short)f2bf(b[1]);
  v[6] = (short)f2bf(b[2]); v[7] = (short)f2bf(b[3]);
  return v;
}

static __device__ inline void gll16(const void* g, void* l) {
  __builtin_amdgcn_global_load_lds(
      (const __attribute__((address_space(1))) void*)g,
      (__attribute__((address_space(3))) void*)l, 16, 0, 0);
}

// ---------------- prep: t/xs + x->bf16 + zero split-K counters ----------------
__global__ __launch_bounds__(256) void tk_kernel(
    const float* __restrict__ x, const float* __restrict__ B,
    float* __restrict__ t, float* __restrict__ xs,
    unsigned short* __restrict__ xbf, unsigned* __restrict__ cnt) {
  const int tid = threadIdx.x;
  const int s = blockIdx.x;
  if (s == 0 && tid < 128 && cnt) cnt[tid] = 0;
  const float* xr = x + (long)s * KDIM;
  float a0 = 0.f, a1 = 0.f, a2 = 0.f, a3 = 0.f, a4 = 0.f;
  for (int k = tid * 4; k < KDIM; k += 1024) {
    f32x4 xv = *(const f32x4*)&xr[k];
    if (xbf) {
      bf16x4 bv;
      bv[0] = (short)f2bf(xv[0]); bv[1] = (short)f2bf(xv[1]);
      bv[2] = (short)f2bf(xv[2]); bv[3] = (short)f2bf(xv[3]);
      *(bf16x4*)&xbf[(long)s * KDIM + k] = bv;
    }
    f32x4 b0 = *(const f32x4*)&B[0 * KDIM + k];
    f32x4 b1 = *(const f32x4*)&B[1 * KDIM + k];
    f32x4 b2 = *(const f32x4*)&B[2 * KDIM + k];
    f32x4 b3 = *(const f32x4*)&B[3 * KDIM + k];
    a0 += xv[0]*b0[0] + xv[1]*b0[1] + xv[2]*b0[2] + xv[3]*b0[3];
    a1 += xv[0]*b1[0] + xv[1]*b1[1] + xv[2]*b1[2] + xv[3]*b1[3];
    a2 += xv[0]*b2[0] + xv[1]*b2[1] + xv[2]*b2[2] + xv[3]*b2[3];
    a3 += xv[0]*b3[0] + xv[1]*b3[1] + xv[2]*b3[2] + xv[3]*b3[3];
    a4 += xv[0] + xv[1] + xv[2] + xv[3];
  }
  #pragma unroll
  for (int off = 32; off; off >>= 1) {
    a0 += __shfl_down(a0, off, 64);
    a1 += __shfl_down(a1, off, 64);
    a2 += __shfl_down(a2, off, 64);
    a3 += __shfl_down(a3, off, 64);
    a4 += __shfl_down(a4, off, 64);
  }
  __shared__ float red[4][5];
  int w = tid >> 6, l = tid & 63;
  if (l == 0) { red[w][0]=a0; red[w][1]=a1; red[w][2]=a2; red[w][3]=a3; red[w][4]=a4; }
  __syncthreads();
  if (tid == 0) {
    t[0 * MDIM + s] = red[0][0] + red[1][0] + red[2][0] + red[3][0];
    t[1 * MDIM + s] = red[0][1] + red[1][1] + red[2][1] + red[3][1];
    t[2 * MDIM + s] = red[0][2] + red[1][2] + red[2][2] + red[3][2];
    t[3 * MDIM + s] = red[0][3] + red[1][3] + red[2][3] + red[3][3];
    xs[s]           = red[0][4] + red[1][4] + red[2][4] + red[3][4];
  }
}

// ---------------- main GEMM: 8 waves, ring-3 x, banked W, counted vmcnt -----
// LDS swizzle (both operands): 16B chunk c of row r stored at c ^ (r&7).
// Per-wave barrier invariant: pending vmem == gll(kt+2)[2] + W(kt+2)[4] == 6.
template<int NSPLIT, bool FUSED>
__global__ __launch_bounds__(512, 4) void gemm_v13(
    const unsigned short* __restrict__ xb, const float* __restrict__ W,
    const float* __restrict__ A, const float* __restrict__ bias,
    const float* __restrict__ zcw, const float* __restrict__ zcb,
    const float* __restrict__ t, const float* __restrict__ xs,
    float* __restrict__ dst, float* __restrict__ out, unsigned* __restrict__ cnt) {
  __shared__ __align__(16) unsigned short As[3][BM * BK];  // 3 x 16KB
  __shared__ __align__(16) unsigned short Ws[2][BN * BK];  // 2 x 16KB
  __shared__ unsigned lastFlag;

  const int bm = blockIdx.x >> 5;     // 0..3
  const int bn = blockIdx.x & 31;     // 0..31
  const int ks = blockIdx.y;
  const int NTloc = NT / NSPLIT;      // 16 (split) or 64 (fused) -- even
  const int kbase = ks * (KDIM / NSPLIT);

  const int tid = threadIdx.x;
  const int lane = tid & 63;
  const int wv = tid >> 6;            // 0..7
  const int wm = wv >> 2;             // 0..1 : rows wm*64..+63
  const int wn = wv & 3;              // 0..3 : cols wn*32..+31

  // ---- x staging (gll16): 2 instrs/wave; instr j covers rows j*64+wv*8+(lane>>3)
  const int srow8 = lane >> 3;
  const int schk = (lane & 7) ^ srow8;            // pre-swizzled source chunk
  const unsigned short* xsrc[2];
  #pragma unroll
  for (int j = 0; j < 2; ++j)
    xsrc[j] = xb + (long)(bm * BM + j * 64 + wv * 8 + srow8) * KDIM + kbase + schk * 8;

  auto XSTAGE = [&](int kt, int slot) {
    const int koff = kt * BK;
    #pragma unroll
    for (int j = 0; j < 2; ++j)
      gll16(xsrc[j] + koff, &As[slot][j * 4096 + wv * 512]);
  };

  // ---- W: 4 loads/wave; rows wv*16 + (lane>>4) + i*4, fp32 16B chunk (lane&15)
  const int wrow = wv * 16 + (lane >> 4);
  const float* wgp = W + (long)(bn * BN + wrow) * KDIM + kbase + (lane & 15) * 4;
  const int wc = (lane & 15) >> 1;
  const int wh = (lane & 1) * 4;

  f32x4 wrA[4], wrB[4];
  auto WISSUE = [&](f32x4 (&wr)[4], int kt) {
    const float* base = wgp + kt * BK;
    #pragma unroll
    for (int i = 0; i < 4; ++i) {
      const float* p = base + (long)i * 4 * KDIM;
      asm volatile("global_load_dwordx4 %0, %1, off"
                   : "=v"(wr[i]) : "v"(p) : "memory");
    }
  };
  auto WWRITE = [&](const f32x4 (&wr)[4], int slot) {
    #pragma unroll
    for (int i = 0; i < 4; ++i) {
      const int r = wrow + i * 4;
      u16x4 v;
      v[0] = f2bf(wr[i][0]); v[1] = f2bf(wr[i][1]);
      v[2] = f2bf(wr[i][2]); v[3] = f2bf(wr[i][3]);
      *(u16x4*)&Ws[slot][r * 64 + ((wc ^ (r & 7)) << 3) + wh] = v;
    }
  };

  // ---- fragment read map ----
  const int fr = lane & 15;
  const int q = lane >> 4;
  const int frs = fr & 7;

  f32x4 acc[4][2] = {};

  auto COMPUTE = [&](int xslot, int wslot) {
    #pragma unroll
    for (int kseg = 0; kseg < 2; ++kseg) {
      const int c = ((kseg * 4 + q) ^ frs) * 8;
      bf16x8 af[4], wf[2];
      #pragma unroll
      for (int mi = 0; mi < 4; ++mi)
        af[mi] = *(const bf16x8*)&As[xslot][(wm * 64 + mi * 16 + fr) * 64 + c];
      #pragma unroll
      for (int ni = 0; ni < 2; ++ni)
        wf[ni] = *(const bf16x8*)&Ws[wslot][(wn * 32 + ni * 16 + fr) * 64 + c];
      __builtin_amdgcn_s_setprio(1);
      #pragma unroll
      for (int mi = 0; mi < 4; ++mi)
        #pragma unroll
        for (int ni = 0; ni < 2; ++ni)
          acc[mi][ni] = __builtin_amdgcn_mfma_f32_16x16x32_bf16(
              af[mi], wf[ni], acc[mi][ni], 0, 0, 0);
      __builtin_amdgcn_s_setprio(0);
    }
  };

  // ---- prologue (per-wave pending counts in comments) ----
  WISSUE(wrA, 0);            // 4
  XSTAGE(0, 0);              // 6
  XSTAGE(1, 1);              // 8
  WISSUE(wrB, 1);            // 12
  VMCNT(8); SCHED0();        // W(0) landed; leaves gll0+gll1+W1 = 8
  WWRITE(wrA, 0);
  VMCNT(6); SCHED0();        // gll(0) landed; leaves gll1+W1 = 6 = invariant
  LGKM0();
  __builtin_amdgcn_s_barrier();
  SCHED0();

  // ---- steady: phase kt stages tile kt+2, consumes W(kt+1), computes kt ----
  #define BODY(KT, BFILL, BCON)                                   \
    do {                                                          \
      XSTAGE((KT) + 2, ((KT) + 2) % 3);  /* +2 -> 8 */            \
      WISSUE(BFILL, (KT) + 2);           /* +4 -> 12 */           \
      VMCNT(6); SCHED0();                /* gll(kt+1)+W(kt+1) landed */ \
      WWRITE(BCON, ((KT) + 1) & 1);                               \
      COMPUTE((KT) % 3, (KT) & 1);                                \
      LGKM0();                                                    \
      __builtin_amdgcn_s_barrier();                               \
      SCHED0();                                                   \
    } while (0)

  for (int kt = 0; kt < NTloc - 2; kt += 2) {
    BODY(kt, wrA, wrB);        // even: fill wrA with W(kt+2), consume wrB=W(kt+1)
    BODY(kt + 1, wrB, wrA);
  }
  #undef BODY
  // phase NTloc-2: no staging; drain, consume wrB=W(NTloc-1)
  VMCNT(0); SCHED0();
  WWRITE(wrB, (NTloc - 1) & 1);
  COMPUTE((NTloc - 2) % 3, (NTloc - 2) & 1);
  LGKM0();
  __builtin_amdgcn_s_barrier();
  SCHED0();
  // phase NTloc-1
  COMPUTE((NTloc - 1) % 3, (NTloc - 1) & 1);

  // ---- epilogue ----
  const int s0 = bm * BM + wm * 64;
  const int o0 = bn * BN + wn * 32;
  if (FUSED) {
    const float zw8 = zcw[0] * 8.0f;
    const float zb = zcb[0];
    #pragma unroll
    for (int mi = 0; mi < 4; ++mi) {
      const int sb = s0 + mi * 16 + q * 4;
      f32x4 t0 = *(const f32x4*)&t[0 * MDIM + sb];
      f32x4 t1 = *(const f32x4*)&t[1 * MDIM + sb];
      f32x4 t2 = *(const f32x4*)&t[2 * MDIM + sb];
      f32x4 t3 = *(const f32x4*)&t[3 * MDIM + sb];
      f32x4 x4 = *(const f32x4*)&xs[sb];
      #pragma unroll
      for (int ni = 0; ni < 2; ++ni) {
        const int o = o0 + ni * 16 + fr;
        f32x4 a4 = *(const f32x4*)&A[o * 4];
        const float bo = bias[o];
        #pragma unroll
        for (int j = 0; j < 4; ++j) {
          float corr = zw8 * (a4[0] * t0[j] + a4[1] * t1[j] + a4[2] * t2[j] + a4[3] * t3[j])
                     + zb * x4[j] + bo;
          out[(long)(sb + j) * NDIM + o] = acc[mi][ni][j] + corr;
        }
      }
    }
  } else {
    // 1) write this split's partial
    float* p = dst + (size_t)ks * MDIM * NDIM;
    #pragma unroll
    for (int mi = 0; mi < 4; ++mi) {
      const int sb = s0 + mi * 16 + q * 4;
      #pragma unroll
      for (int ni = 0; ni < 2; ++ni) {
        const int o = o0 + ni * 16 + fr;
        #pragma unroll
        for (int j = 0; j < 4; ++j)
          p[(long)(sb + j) * NDIM + o] = acc[mi][ni][j];
      }
    }
    // 2) release + per-tile arrival count
    __threadfence();
    __syncthreads();
    if (tid == 0)
      lastFlag = (atomicAdd(&cnt[blockIdx.x], 1u) == (unsigned)(NSPLIT - 1));
    __syncthreads();
    // 3) last-arriving block reduces all NSPLIT partials (fixed order) + corr
    if (lastFlag) {
      __threadfence();   // acquire: invalidate local caches (cross-XCD, G16)
      const float zw8 = zcw[0] * 8.0f;
      const float zb = zcb[0];
      #pragma unroll
      for (int mi = 0; mi < 4; ++mi) {
        const int sb = s0 + mi * 16 + q * 4;
        f32x4 t0 = *(const f32x4*)&t[0 * MDIM + sb];
        f32x4 t1 = *(const f32x4*)&t[1 * MDIM + sb];
        f32x4 t2 = *(const f32x4*)&t[2 * MDIM + sb];
        f32x4 t3 = *(const f32x4*)&t[3 * MDIM + sb];
        f32x4 x4 = *(const f32x4*)&xs[sb];
        #pragma unroll
        for (int ni = 0; ni < 2; ++ni) {
          const int o = o0 + ni * 16 + fr;
          f32x4 a4 = *(const f32x4*)&A[o * 4];
          const float bo = bias[o];
          #pragma unroll
          for (int j = 0; j < 4; ++j) {
            const long idx = (long)(sb + j) * NDIM + o;
            float s = 0.f;
            #pragma unroll
            for (int k2 = 0; k2 < NSPLIT; ++k2)
              s += dst[(size_t)k2 * MDIM * NDIM + idx];
            float corr = zw8 * (a4[0] * t0[j] + a4[1] * t1[j] + a4[2] * t2[j] + a4[3] * t3[j])
                       + zb * x4[j] + bo;
            out[idx] = s + corr;
          }
        }
      }
    }
  }
}

// ---------------- fallback (ws tiny): reg-staged fused GEMM --------------
__global__ __launch_bounds__(256) void gemm_fallback(
    const float* __restrict__ x, const float* __restrict__ W,
    const float* __restrict__ A, const float* __restrict__ bias,
    const float* __restrict__ zcw, const float* __restrict__ zcb,
    const float* __restrict__ t, const float* __restrict__ xs,
    float* __restrict__ out) {
  __shared__ __align__(16) unsigned short Asf[2][64 * 64];
  __shared__ __align__(16) unsigned short Wsf[2][64 * 64];
  const int bid = blockIdx.x;
  const int bn = bid & 63, bm = bid >> 6;
  const int tid = threadIdx.x, lane = tid & 63, wid = tid >> 6;
  const int wm = wid >> 1, wn = wid & 1;
  const int srow = tid >> 2, sc0 = (tid & 3) * 16;
  const float* xg = x + (long)(bm * 64 + srow) * KDIM + sc0;
  const float* wg = W + (long)(bn * 64 + srow) * KDIM + sc0;
  const int off0 = (srow * 64 + sc0) ^ ((srow & 7) << 3);
  const int off1 = (srow * 64 + sc0 + 8) ^ ((srow & 7) << 3);
  const int fr = lane & 15, fk = (lane >> 4) * 8;
  f32x4 acc[2][2] = {};
  f32x4 xv0, xv1, xv2, xv3, wv0, wv1, wv2, wv3;
  xv0 = *(const f32x4*)(xg);      xv1 = *(const f32x4*)(xg + 4);
  xv2 = *(const f32x4*)(xg + 8);  xv3 = *(const f32x4*)(xg + 12);
  wv0 = *(const f32x4*)(wg);      wv1 = *(const f32x4*)(wg + 4);
  wv2 = *(const f32x4*)(wg + 8);  wv3 = *(const f32x4*)(wg + 12);
  *(bf16x8*)&Asf[0][off0] = pack8(xv0, xv1);
  *(bf16x8*)&Asf[0][off1] = pack8(xv2, xv3);
  *(bf16x8*)&Wsf[0][off0] = pack8(wv0, wv1);
  *(bf16x8*)&Wsf[0][off1] = pack8(wv2, wv3);
  __syncthreads();
  for (int kt = 0; kt < KDIM / 64; ++kt) {
    const int cur = kt & 1;
    if (kt + 1 < KDIM / 64) {
      const int off = (kt + 1) * 64;
      xv0 = *(const f32x4*)(xg + off);      xv1 = *(const f32x4*)(xg + off + 4);
      xv2 = *(const f32x4*)(xg + off + 8);  xv3 = *(const f32x4*)(xg + off + 12);
      wv0 = *(const f32x4*)(wg + off);      wv1 = *(const f32x4*)(wg + off + 4);
      wv2 = *(const f32x4*)(wg + off + 8);  wv3 = *(const f32x4*)(wg + off + 12);
    }
    #pragma unroll
    for (int kss = 0; kss < 2; ++kss) {
      const int kk = kss * 32 + fk;
      const int ra0 = wm * 32 + fr, ra1 = ra0 + 16;
      const int rb0 = wn * 32 + fr, rb1 = rb0 + 16;
      bf16x8 a0 = *(const bf16x8*)&Asf[cur][(ra0 * 64 + kk) ^ ((ra0 & 7) << 3)];
      bf16x8 a1 = *(const bf16x8*)&Asf[cur][(ra1 * 64 + kk) ^ ((ra1 & 7) << 3)];
      bf16x8 b0 = *(const bf16x8*)&Wsf[cur][(rb0 * 64 + kk) ^ ((rb0 & 7) << 3)];
      bf16x8 b1 = *(const bf16x8*)&Wsf[cur][(rb1 * 64 + kk) ^ ((rb1 & 7) << 3)];
      acc[0][0] = __builtin_amdgcn_mfma_f32_16x16x32_bf16(a0, b0, acc[0][0], 0, 0, 0);
      acc[0][1] = __builtin_amdgcn_mfma_f32_16x16x32_bf16(a0, b1, acc[0][1], 0, 0, 0);
      acc[1][0] = __builtin_amdgcn_mfma_f32_16x16x32_bf16(a1, b0, acc[1][0], 0, 0, 0);
      acc[1][1] = __builtin_amdgcn_mfma_f32_16x16x32_bf16(a1, b1, acc[1][1], 0, 0, 0);
    }
    if (kt + 1 < KDIM / 64) {
      const int nxt = cur ^ 1;
      *(bf16x8*)&Asf[nxt][off0] = pack8(xv0, xv1);
      *(bf16x8*)&Asf[nxt][off1] = pack8(xv2, xv3);
      *(bf16x8*)&Wsf[nxt][off0] = pack8(wv0, wv1);
      *(bf16x8*)&Wsf[nxt][off1] = pack8(wv2, wv3);
    }
    __syncthreads();
  }
  const float zw8 = zcw[0] * 8.0f;
  const float zb = zcb[0];
  const int s0 = bm * 64 + wm * 32;
  const int o0 = bn * 64 + wn * 32;
  #pragma unroll
  for (int mi = 0; mi < 2; ++mi) {
    const int sb = s0 + mi * 16 + ((lane >> 4) * 4);
    f32x4 t0 = *(const f32x4*)&t[0 * MDIM + sb];
    f32x4 t1 = *(const f32x4*)&t[1 * MDIM + sb];
    f32x4 t2 = *(const f32x4*)&t[2 * MDIM + sb];
    f32x4 t3 = *(const f32x4*)&t[3 * MDIM + sb];
    f32x4 x4 = *(const f32x4*)&xs[sb];
    #pragma unroll
    for (int ni = 0; ni < 2; ++ni) {
      const int o = o0 + ni * 16 + fr;
      f32x4 a4 = *(const f32x4*)&A[o * 4];
      const float bo = bias[o];
      #pragma unroll
      for (int j = 0; j < 4; ++j) {
        float corr = zw8 * (a4[0] * t0[j] + a4[1] * t1[j] + a4[2] * t2[j] + a4[3] * t3[j])
                   + zb * x4[j] + bo;
        out[(long)(sb + j) * NDIM + o] = acc[mi][ni][j] + corr;
      }
    }
  }
}

extern "C" void kernel_launch(void* const* d_in, const int* in_sizes, int n_in,
                              void* d_out, int out_size, void* d_ws, size_t ws_size,
                              hipStream_t stream) {
  const float* x    = (const float*)d_in[0];
  const float* W    = (const float*)d_in[1];
  const float* A    = (const float*)d_in[2];
  const float* B    = (const float*)d_in[3];
  const float* zcw  = (const float*)d_in[4];
  const float* zcb  = (const float*)d_in[5];
  const float* bias = (const float*)d_in[6];
  float* out = (float*)d_out;

  float* t  = (float*)d_ws;                       // [4][512]
  float* xs = t + 4 * MDIM;                       // [512]
  unsigned* cnt = (unsigned*)(t + 2560);          // [128] split-K tile counters
  unsigned short* xbf = (unsigned short*)(t + 4096);          // [512][4096] bf16
  float* pbuf = (float*)(xbf + (size_t)MDIM * KDIM);          // [4][512][4096] f32

  const size_t need_x = 4096u * 4 + (size_t)MDIM * KDIM * 2;
  const size_t need_p = need_x + (size_t)4 * MDIM * NDIM * 4;

  if (ws_size >= need_p) {
    tk_kernel<<<MDIM, 256, 0, stream>>>(x, B, t, xs, xbf, cnt);
    gemm_v13<4, false><<<dim3(4 * 32, 4), 512, 0, stream>>>(
        xbf, W, A, bias, zcw, zcb, t, xs, pbuf, out, cnt);
  } else if (ws_size >= need_x) {
    tk_kernel<<<MDIM, 256, 0, stream>>>(x, B, t, xs, xbf, nullptr);
    gemm_v13<1, true><<<dim3(4 * 32, 1), 512, 0, stream>>>(
        xbf, W, A, bias, zcw, zcb, t, xs, out, out, nullptr);
  } else {
    tk_kernel<<<MDIM, 256, 0, stream>>>(x, B, t, xs, nullptr, nullptr);
    gemm_fallback<<<(MDIM / 64) * (NDIM / 64), 256, 0, stream>>>(
        x, W, A, bias, zcw, zcb, t, xs, out);
  }
}

// Round 14
// 41.834 us; speedup vs baseline: 4.9154x; 4.9154x over previous
//
#include <hip/hip_runtime.h>
#include <hip/hip_bf16.h>

// out[s,o] = sum_k x[s,k]*W[o,k]   (bf16 MFMA)
//   128x128 tile, BK=64, 8 waves (64x32 wave tile), split-K=4.
//   x: bf16 via global_load_lds ring-3. W: fp32 inline-asm loads 1 phase ahead
//   -> cvt_pk -> ds_write (2-slot bf16 LDS). Counted per-wave VMCNT(6).
//   Partials: PACKED BF16, gemm-geometry layout [ks][bid][word][tid] (all
//   accesses block-wide coalesced); separate reduce kernel (fixed-order sum).
// + zc_w*8*sum_r A[o,r]*t[r,s] + zc_b*xsum[s] + bias[o] exact fp32 epilogue.

typedef __attribute__((ext_vector_type(8))) short bf16x8;
typedef __attribute__((ext_vector_type(4))) short bf16x4;
typedef __attribute__((ext_vector_type(4))) unsigned short u16x4;
typedef __attribute__((ext_vector_type(4))) float f32x4;

#define MDIM 512
#define NDIM 4096
#define KDIM 4096
#define BM 128
#define BN 128
#define BK 64
#define NT (KDIM / BK)   // 64

#define VMCNT(n) asm volatile("s_waitcnt vmcnt(" #n ")" ::: "memory")
#define LGKM0()  asm volatile("s_waitcnt lgkmcnt(0)" ::: "memory")
#define SCHED0() __builtin_amdgcn_sched_barrier(0)

static __device__ inline unsigned short f2bf(float f) {
  return __bfloat16_as_ushort(__float2bfloat16(f));  // v_cvt_pk_bf16_f32
}

static __device__ inline float bflo(unsigned u) {
  union { unsigned x; float f; } c; c.x = u << 16; return c.f;
}
static __device__ inline float bfhi(unsigned u) {
  union { unsigned x; float f; } c; c.x = u & 0xffff0000u; return c.f;
}

static __device__ inline bf16x8 pack8(f32x4 a, f32x4 b) {
  bf16x8 v;
  v[0] = (short)f2bf(a[0]); v[1] = (short)f2bf(a[1]);
  v[2] = (short)f2bf(a[2]); v[3] = (short)f2bf(a[3]);
  v[4] = (short)f2bf(b[0]); v[5] = (short)f2bf(b[1]);
  v[6] = (short)f2bf(b[2]); v[7] = (short)f2bf(b[3]);
  return v;
}

static __device__ inline void gll16(const void* g, void* l) {
  __builtin_amdgcn_global_load_lds(
      (const __attribute__((address_space(1))) void*)g,
      (__attribute__((address_space(3))) void*)l, 16, 0, 0);
}

// ---------------- prep: t/xs + x->bf16 ----------------
__global__ __launch_bounds__(256) void tk_kernel(
    const float* __restrict__ x, const float* __restrict__ B,
    float* __restrict__ t, float* __restrict__ xs,
    unsigned short* __restrict__ xbf) {
  const int tid = threadIdx.x;
  const int s = blockIdx.x;
  const float* xr = x + (long)s * KDIM;
  float a0 = 0.f, a1 = 0.f, a2 = 0.f, a3 = 0.f, a4 = 0.f;
  for (int k = tid * 4; k < KDIM; k += 1024) {
    f32x4 xv = *(const f32x4*)&xr[k];
    if (xbf) {
      bf16x4 bv;
      bv[0] = (short)f2bf(xv[0]); bv[1] = (short)f2bf(xv[1]);
      bv[2] = (short)f2bf(xv[2]); bv[3] = (short)f2bf(xv[3]);
      *(bf16x4*)&xbf[(long)s * KDIM + k] = bv;
    }
    f32x4 b0 = *(const f32x4*)&B[0 * KDIM + k];
    f32x4 b1 = *(const f32x4*)&B[1 * KDIM + k];
    f32x4 b2 = *(const f32x4*)&B[2 * KDIM + k];
    f32x4 b3 = *(const f32x4*)&B[3 * KDIM + k];
    a0 += xv[0]*b0[0] + xv[1]*b0[1] + xv[2]*b0[2] + xv[3]*b0[3];
    a1 += xv[0]*b1[0] + xv[1]*b1[1] + xv[2]*b1[2] + xv[3]*b1[3];
    a2 += xv[0]*b2[0] + xv[1]*b2[1] + xv[2]*b2[2] + xv[3]*b2[3];
    a3 += xv[0]*b3[0] + xv[1]*b3[1] + xv[2]*b3[2] + xv[3]*b3[3];
    a4 += xv[0] + xv[1] + xv[2] + xv[3];
  }
  #pragma unroll
  for (int off = 32; off; off >>= 1) {
    a0 += __shfl_down(a0, off, 64);
    a1 += __shfl_down(a1, off, 64);
    a2 += __shfl_down(a2, off, 64);
    a3 += __shfl_down(a3, off, 64);
    a4 += __shfl_down(a4, off, 64);
  }
  __shared__ float red[4][5];
  int w = tid >> 6, l = tid & 63;
  if (l == 0) { red[w][0]=a0; red[w][1]=a1; red[w][2]=a2; red[w][3]=a3; red[w][4]=a4; }
  __syncthreads();
  if (tid == 0) {
    t[0 * MDIM + s] = red[0][0] + red[1][0] + red[2][0] + red[3][0];
    t[1 * MDIM + s] = red[0][1] + red[1][1] + red[2][1] + red[3][1];
    t[2 * MDIM + s] = red[0][2] + red[1][2] + red[2][2] + red[3][2];
    t[3 * MDIM + s] = red[0][3] + red[1][3] + red[2][3] + red[3][3];
    xs[s]           = red[0][4] + red[1][4] + red[2][4] + red[3][4];
  }
}

// ---------------- main GEMM: 8 waves, ring-3 x, banked W, counted vmcnt -----
// LDS swizzle (both operands): 16B chunk c of row r stored at c ^ (r&7).
// Per-wave barrier invariant: pending vmem == gll(kt+2)[2] + W(kt+2)[4] == 6.
template<int NSPLIT, bool FUSED>
__global__ __launch_bounds__(512, 4) void gemm_v14(
    const unsigned short* __restrict__ xb, const float* __restrict__ W,
    const float* __restrict__ A, const float* __restrict__ bias,
    const float* __restrict__ zcw, const float* __restrict__ zcb,
    const float* __restrict__ t, const float* __restrict__ xs,
    unsigned* __restrict__ pbuf, float* __restrict__ out) {
  __shared__ __align__(16) unsigned short As[3][BM * BK];  // 3 x 16KB
  __shared__ __align__(16) unsigned short Ws[2][BN * BK];  // 2 x 16KB

  const int bm = blockIdx.x >> 5;     // 0..3
  const int bn = blockIdx.x & 31;     // 0..31
  const int ks = blockIdx.y;
  const int NTloc = NT / NSPLIT;      // 16 (split) or 64 (fused) -- even
  const int kbase = ks * (KDIM / NSPLIT);

  const int tid = threadIdx.x;
  const int lane = tid & 63;
  const int wv = tid >> 6;            // 0..7
  const int wm = wv >> 2;             // 0..1 : rows wm*64..+63
  const int wn = wv & 3;              // 0..3 : cols wn*32..+31

  // ---- x staging (gll16): 2 instrs/wave; instr j covers rows j*64+wv*8+(lane>>3)
  const int srow8 = lane >> 3;
  const int schk = (lane & 7) ^ srow8;            // pre-swizzled source chunk
  const unsigned short* xsrc[2];
  #pragma unroll
  for (int j = 0; j < 2; ++j)
    xsrc[j] = xb + (long)(bm * BM + j * 64 + wv * 8 + srow8) * KDIM + kbase + schk * 8;

  auto XSTAGE = [&](int kt, int slot) {
    const int koff = kt * BK;
    #pragma unroll
    for (int j = 0; j < 2; ++j)
      gll16(xsrc[j] + koff, &As[slot][j * 4096 + wv * 512]);
  };

  // ---- W: 4 loads/wave; rows wv*16 + (lane>>4) + i*4, fp32 16B chunk (lane&15)
  const int wrow = wv * 16 + (lane >> 4);
  const float* wgp = W + (long)(bn * BN + wrow) * KDIM + kbase + (lane & 15) * 4;
  const int wc = (lane & 15) >> 1;
  const int wh = (lane & 1) * 4;

  f32x4 wrA[4], wrB[4];
  auto WISSUE = [&](f32x4 (&wr)[4], int kt) {
    const float* base = wgp + kt * BK;
    #pragma unroll
    for (int i = 0; i < 4; ++i) {
      const float* p = base + (long)i * 4 * KDIM;
      asm volatile("global_load_dwordx4 %0, %1, off"
                   : "=v"(wr[i]) : "v"(p) : "memory");
    }
  };
  auto WWRITE = [&](const f32x4 (&wr)[4], int slot) {
    #pragma unroll
    for (int i = 0; i < 4; ++i) {
      const int r = wrow + i * 4;
      u16x4 v;
      v[0] = f2bf(wr[i][0]); v[1] = f2bf(wr[i][1]);
      v[2] = f2bf(wr[i][2]); v[3] = f2bf(wr[i][3]);
      *(u16x4*)&Ws[slot][r * 64 + ((wc ^ (r & 7)) << 3) + wh] = v;
    }
  };

  // ---- fragment read map ----
  const int fr = lane & 15;
  const int q = lane >> 4;
  const int frs = fr & 7;

  f32x4 acc[4][2] = {};

  auto COMPUTE = [&](int xslot, int wslot) {
    #pragma unroll
    for (int kseg = 0; kseg < 2; ++kseg) {
      const int c = ((kseg * 4 + q) ^ frs) * 8;
      bf16x8 af[4], wf[2];
      #pragma unroll
      for (int mi = 0; mi < 4; ++mi)
        af[mi] = *(const bf16x8*)&As[xslot][(wm * 64 + mi * 16 + fr) * 64 + c];
      #pragma unroll
      for (int ni = 0; ni < 2; ++ni)
        wf[ni] = *(const bf16x8*)&Ws[wslot][(wn * 32 + ni * 16 + fr) * 64 + c];
      __builtin_amdgcn_s_setprio(1);
      #pragma unroll
      for (int mi = 0; mi < 4; ++mi)
        #pragma unroll
        for (int ni = 0; ni < 2; ++ni)
          acc[mi][ni] = __builtin_amdgcn_mfma_f32_16x16x32_bf16(
              af[mi], wf[ni], acc[mi][ni], 0, 0, 0);
      __builtin_amdgcn_s_setprio(0);
    }
  };

  // ---- prologue (per-wave pending counts in comments) ----
  WISSUE(wrA, 0);            // 4
  XSTAGE(0, 0);              // 6
  XSTAGE(1, 1);              // 8
  WISSUE(wrB, 1);            // 12
  VMCNT(8); SCHED0();        // W(0) landed; leaves gll0+gll1+W1 = 8
  WWRITE(wrA, 0);
  VMCNT(6); SCHED0();        // gll(0) landed; leaves gll1+W1 = 6 = invariant
  LGKM0();
  __builtin_amdgcn_s_barrier();
  SCHED0();

  // ---- steady: phase kt stages tile kt+2, consumes W(kt+1), computes kt ----
  #define BODY(KT, BFILL, BCON)                                   \
    do {                                                          \
      XSTAGE((KT) + 2, ((KT) + 2) % 3);  /* +2 -> 8 */            \
      WISSUE(BFILL, (KT) + 2);           /* +4 -> 12 */           \
      VMCNT(6); SCHED0();                /* gll(kt+1)+W(kt+1) landed */ \
      WWRITE(BCON, ((KT) + 1) & 1);                               \
      COMPUTE((KT) % 3, (KT) & 1);                                \
      LGKM0();                                                    \
      __builtin_amdgcn_s_barrier();                               \
      SCHED0();                                                   \
    } while (0)

  for (int kt = 0; kt < NTloc - 2; kt += 2) {
    BODY(kt, wrA, wrB);        // even: fill wrA with W(kt+2), consume wrB=W(kt+1)
    BODY(kt + 1, wrB, wrA);
  }
  #undef BODY
  // phase NTloc-2: no staging; drain, consume wrB=W(NTloc-1)
  VMCNT(0); SCHED0();
  WWRITE(wrB, (NTloc - 1) & 1);
  COMPUTE((NTloc - 2) % 3, (NTloc - 2) & 1);
  LGKM0();
  __builtin_amdgcn_s_barrier();
  SCHED0();
  // phase NTloc-1
  COMPUTE((NTloc - 1) % 3, (NTloc - 1) & 1);

  // ---- epilogue ----
  const int s0 = bm * BM + wm * 64;
  const int o0 = bn * BN + wn * 32;
  if (FUSED) {
    const float zw8 = zcw[0] * 8.0f;
    const float zb = zcb[0];
    #pragma unroll
    for (int mi = 0; mi < 4; ++mi) {
      const int sb = s0 + mi * 16 + q * 4;
      f32x4 t0 = *(const f32x4*)&t[0 * MDIM + sb];
      f32x4 t1 = *(const f32x4*)&t[1 * MDIM + sb];
      f32x4 t2 = *(const f32x4*)&t[2 * MDIM + sb];
      f32x4 t3 = *(const f32x4*)&t[3 * MDIM + sb];
      f32x4 x4 = *(const f32x4*)&xs[sb];
      #pragma unroll
      for (int ni = 0; ni < 2; ++ni) {
        const int o = o0 + ni * 16 + fr;
        f32x4 a4 = *(const f32x4*)&A[o * 4];
        const float bo = bias[o];
        #pragma unroll
        for (int j = 0; j < 4; ++j) {
          float corr = zw8 * (a4[0] * t0[j] + a4[1] * t1[j] + a4[2] * t2[j] + a4[3] * t3[j])
                     + zb * x4[j] + bo;
          out[(long)(sb + j) * NDIM + o] = acc[mi][ni][j] + corr;
        }
      }
    }
  } else {
    // packed-bf16 partial store: word w of thread tid for (ks, bid) at
    // pbuf[((ks*128 + bid)*16 + w)*512 + tid] -- block-wide coalesced.
    unsigned* p = pbuf + ((size_t)ks * 128 + blockIdx.x) * 16 * 512 + tid;
    #pragma unroll
    for (int mi = 0; mi < 4; ++mi)
      #pragma unroll
      for (int ni = 0; ni < 2; ++ni)
        #pragma unroll
        for (int h = 0; h < 2; ++h) {
          unsigned uw = (unsigned)f2bf(acc[mi][ni][2 * h])
                      | ((unsigned)f2bf(acc[mi][ni][2 * h + 1]) << 16);
          p[(size_t)(mi * 4 + ni * 2 + h) * 512] = uw;
        }
  }
}

// ---------------- reduce: sum 4 bf16 partials (fixed order) + exact corr ----
__global__ __launch_bounds__(256) void reduce2(
    const unsigned* __restrict__ p,
    const float* __restrict__ A, const float* __restrict__ bias,
    const float* __restrict__ zcw, const float* __restrict__ zcb,
    const float* __restrict__ t, const float* __restrict__ xs,
    float* __restrict__ out) {
  const int gb = blockIdx.x >> 1;                     // gemm block 0..127
  const int tid = ((blockIdx.x & 1) << 8) | threadIdx.x;  // 0..511
  const int bm = gb >> 5, bn = gb & 31;
  const int lane = tid & 63, wv = tid >> 6;
  const int wm = wv >> 2, wn = wv & 3;
  const int fr = lane & 15, q = lane >> 4;
  const size_t kss = (size_t)128 * 16 * 512;
  const unsigned* base = p + (size_t)gb * 16 * 512 + tid;
  const float zw8 = zcw[0] * 8.0f;
  const float zb = zcb[0];
  const int s0 = bm * BM + wm * 64;
  const int o0 = bn * BN + wn * 32;
  #pragma unroll
  for (int mi = 0; mi < 4; ++mi) {
    const int sb = s0 + mi * 16 + q * 4;
    f32x4 t0 = *(const f32x4*)&t[0 * MDIM + sb];
    f32x4 t1 = *(const f32x4*)&t[1 * MDIM + sb];
    f32x4 t2 = *(const f32x4*)&t[2 * MDIM + sb];
    f32x4 t3 = *(const f32x4*)&t[3 * MDIM + sb];
    f32x4 x4 = *(const f32x4*)&xs[sb];
    #pragma unroll
    for (int ni = 0; ni < 2; ++ni) {
      const int o = o0 + ni * 16 + fr;
      f32x4 a4 = *(const f32x4*)&A[o * 4];
      const float bo = bias[o];
      #pragma unroll
      for (int h = 0; h < 2; ++h) {
        const size_t woff = (size_t)(mi * 4 + ni * 2 + h) * 512;
        unsigned u0 = base[woff];
        unsigned u1 = base[kss + woff];
        unsigned u2 = base[2 * kss + woff];
        unsigned u3 = base[3 * kss + woff];
        float vlo = (bflo(u0) + bflo(u1)) + (bflo(u2) + bflo(u3));
        float vhi = (bfhi(u0) + bfhi(u1)) + (bfhi(u2) + bfhi(u3));
        const int j0 = 2 * h, j1 = 2 * h + 1;
        float c0 = zw8 * (a4[0]*t0[j0] + a4[1]*t1[j0] + a4[2]*t2[j0] + a4[3]*t3[j0])
                 + zb * x4[j0] + bo;
        float c1 = zw8 * (a4[0]*t0[j1] + a4[1]*t1[j1] + a4[2]*t2[j1] + a4[3]*t3[j1])
                 + zb * x4[j1] + bo;
        out[(long)(sb + j0) * NDIM + o] = vlo + c0;
        out[(long)(sb + j1) * NDIM + o] = vhi + c1;
      }
    }
  }
}

// ---------------- fallback (ws tiny): reg-staged fused GEMM --------------
__global__ __launch_bounds__(256) void gemm_fallback(
    const float* __restrict__ x, const float* __restrict__ W,
    const float* __restrict__ A, const float* __restrict__ bias,
    const float* __restrict__ zcw, const float* __restrict__ zcb,
    const float* __restrict__ t, const float* __restrict__ xs,
    float* __restrict__ out) {
  __shared__ __align__(16) unsigned short Asf[2][64 * 64];
  __shared__ __align__(16) unsigned short Wsf[2][64 * 64];
  const int bid = blockIdx.x;
  const int bn = bid & 63, bm = bid >> 6;
  const int tid = threadIdx.x, lane = tid & 63, wid = tid >> 6;
  const int wm = wid >> 1, wn = wid & 1;
  const int srow = tid >> 2, sc0 = (tid & 3) * 16;
  const float* xg = x + (long)(bm * 64 + srow) * KDIM + sc0;
  const float* wg = W + (long)(bn * 64 + srow) * KDIM + sc0;
  const int off0 = (srow * 64 + sc0) ^ ((srow & 7) << 3);
  const int off1 = (srow * 64 + sc0 + 8) ^ ((srow & 7) << 3);
  const int fr = lane & 15, fk = (lane >> 4) * 8;
  f32x4 acc[2][2] = {};
  f32x4 xv0, xv1, xv2, xv3, wv0, wv1, wv2, wv3;
  xv0 = *(const f32x4*)(xg);      xv1 = *(const f32x4*)(xg + 4);
  xv2 = *(const f32x4*)(xg + 8);  xv3 = *(const f32x4*)(xg + 12);
  wv0 = *(const f32x4*)(wg);      wv1 = *(const f32x4*)(wg + 4);
  wv2 = *(const f32x4*)(wg + 8);  wv3 = *(const f32x4*)(wg + 12);
  *(bf16x8*)&Asf[0][off0] = pack8(xv0, xv1);
  *(bf16x8*)&Asf[0][off1] = pack8(xv2, xv3);
  *(bf16x8*)&Wsf[0][off0] = pack8(wv0, wv1);
  *(bf16x8*)&Wsf[0][off1] = pack8(wv2, wv3);
  __syncthreads();
  for (int kt = 0; kt < KDIM / 64; ++kt) {
    const int cur = kt & 1;
    if (kt + 1 < KDIM / 64) {
      const int off = (kt + 1) * 64;
      xv0 = *(const f32x4*)(xg + off);      xv1 = *(const f32x4*)(xg + off + 4);
      xv2 = *(const f32x4*)(xg + off + 8);  xv3 = *(const f32x4*)(xg + off + 12);
      wv0 = *(const f32x4*)(wg + off);      wv1 = *(const f32x4*)(wg + off + 4);
      wv2 = *(const f32x4*)(wg + off + 8);  wv3 = *(const f32x4*)(wg + off + 12);
    }
    #pragma unroll
    for (int kss2 = 0; kss2 < 2; ++kss2) {
      const int kk = kss2 * 32 + fk;
      const int ra0 = wm * 32 + fr, ra1 = ra0 + 16;
      const int rb0 = wn * 32 + fr, rb1 = rb0 + 16;
      bf16x8 a0 = *(const bf16x8*)&Asf[cur][(ra0 * 64 + kk) ^ ((ra0 & 7) << 3)];
      bf16x8 a1 = *(const bf16x8*)&Asf[cur][(ra1 * 64 + kk) ^ ((ra1 & 7) << 3)];
      bf16x8 b0 = *(const bf16x8*)&Wsf[cur][(rb0 * 64 + kk) ^ ((rb0 & 7) << 3)];
      bf16x8 b1 = *(const bf16x8*)&Wsf[cur][(rb1 * 64 + kk) ^ ((rb1 & 7) << 3)];
      acc[0][0] = __builtin_amdgcn_mfma_f32_16x16x32_bf16(a0, b0, acc[0][0], 0, 0, 0);
      acc[0][1] = __builtin_amdgcn_mfma_f32_16x16x32_bf16(a0, b1, acc[0][1], 0, 0, 0);
      acc[1][0] = __builtin_amdgcn_mfma_f32_16x16x32_bf16(a1, b0, acc[1][0], 0, 0, 0);
      acc[1][1] = __builtin_amdgcn_mfma_f32_16x16x32_bf16(a1, b1, acc[1][1], 0, 0, 0);
    }
    if (kt + 1 < KDIM / 64) {
      const int nxt = cur ^ 1;
      *(bf16x8*)&Asf[nxt][off0] = pack8(xv0, xv1);
      *(bf16x8*)&Asf[nxt][off1] = pack8(xv2, xv3);
      *(bf16x8*)&Wsf[nxt][off0] = pack8(wv0, wv1);
      *(bf16x8*)&Wsf[nxt][off1] = pack8(wv2, wv3);
    }
    __syncthreads();
  }
  const float zw8 = zcw[0] * 8.0f;
  const float zb = zcb[0];
  const int s0 = bm * 64 + wm * 32;
  const int o0 = bn * 64 + wn * 32;
  #pragma unroll
  for (int mi = 0; mi < 2; ++mi) {
    const int sb = s0 + mi * 16 + ((lane >> 4) * 4);
    f32x4 t0 = *(const f32x4*)&t[0 * MDIM + sb];
    f32x4 t1 = *(const f32x4*)&t[1 * MDIM + sb];
    f32x4 t2 = *(const f32x4*)&t[2 * MDIM + sb];
    f32x4 t3 = *(const f32x4*)&t[3 * MDIM + sb];
    f32x4 x4 = *(const f32x4*)&xs[sb];
    #pragma unroll
    for (int ni = 0; ni < 2; ++ni) {
      const int o = o0 + ni * 16 + fr;
      f32x4 a4 = *(const f32x4*)&A[o * 4];
      const float bo = bias[o];
      #pragma unroll
      for (int j = 0; j < 4; ++j) {
        float corr = zw8 * (a4[0] * t0[j] + a4[1] * t1[j] + a4[2] * t2[j] + a4[3] * t3[j])
                   + zb * x4[j] + bo;
        out[(long)(sb + j) * NDIM + o] = acc[mi][ni][j] + corr;
      }
    }
  }
}

extern "C" void kernel_launch(void* const* d_in, const int* in_sizes, int n_in,
                              void* d_out, int out_size, void* d_ws, size_t ws_size,
                              hipStream_t stream) {
  const float* x    = (const float*)d_in[0];
  const float* W    = (const float*)d_in[1];
  const float* A    = (const float*)d_in[2];
  const float* B    = (const float*)d_in[3];
  const float* zcw  = (const float*)d_in[4];
  const float* zcb  = (const float*)d_in[5];
  const float* bias = (const float*)d_in[6];
  float* out = (float*)d_out;

  float* t  = (float*)d_ws;                       // [4][512]
  float* xs = t + 4 * MDIM;                       // [512]
  unsigned short* xbf = (unsigned short*)(t + 4096);          // [512][4096] bf16
  unsigned* pbuf = (unsigned*)(xbf + (size_t)MDIM * KDIM);    // 16MB packed bf16

  const size_t need_x = 4096u * 4 + (size_t)MDIM * KDIM * 2;
  const size_t need_p = need_x + (size_t)4 * 128 * 16 * 512 * 4;

  if (ws_size >= need_p) {
    tk_kernel<<<MDIM, 256, 0, stream>>>(x, B, t, xs, xbf);
    gemm_v14<4, false><<<dim3(4 * 32, 4), 512, 0, stream>>>(
        xbf, W, A, bias, zcw, zcb, t, xs, pbuf, out);
    reduce2<<<256, 256, 0, stream>>>(pbuf, A, bias, zcw, zcb, t, xs, out);
  } else if (ws_size >= need_x) {
    tk_kernel<<<MDIM, 256, 0, stream>>>(x, B, t, xs, xbf);
    gemm_v14<1, true><<<dim3(4 * 32, 1), 512, 0, stream>>>(
        xbf, W, A, bias, zcw, zcb, t, xs, nullptr, out);
  } else {
    tk_kernel<<<MDIM, 256, 0, stream>>>(x, B, t, xs, nullptr);
    gemm_fallback<<<(MDIM / 64) * (NDIM / 64), 256, 0, stream>>>(
        x, W, A, bias, zcw, zcb, t, xs, out);
  }
}